// Round 13
// baseline (62.975 us; speedup 1.0000x reference)
//
#include <hip/hip_runtime.h>
#include <math.h>

#define B_  2048
#define T_  200
#define D_  64
#define H1_ 80
#define H2_ 40

#define VSTR 72    // s_V row stride (bf16): 144 B rows -> ~2-way banks
#define WSTR 104   // ws W2T row stride (bf16)
#define HSTR 104   // h1 row stride (bf16); cols 80..95 zero pad

// d_ws layout (bytes):
#define WS_A    0        // A[h][f]  bf16 [80][64]
#define WS_C    10240    // C[h][f]  bf16 [80][64]
#define WS_W2T  20480    // W2Tp[g][h] bf16 [48][104]
#define WS_ACT  30464    // W1acT[h][f] f32 [80][64]

typedef __bf16 bf16x8 __attribute__((ext_vector_type(8)));
typedef float  f32x4  __attribute__((ext_vector_type(4)));

__device__ __forceinline__ float sigmoidf_(float x) {
    return __builtin_amdgcn_rcpf(1.0f + __expf(-x));
}

// ---------- prep: block-invariant weight transforms ----------
__global__ __launch_bounds__(256)
void prep_kernel(const float* __restrict__ W1, const float* __restrict__ W2,
                 void* __restrict__ ws)
{
    __bf16* A    = (__bf16*)((char*)ws + WS_A);
    __bf16* C    = (__bf16*)((char*)ws + WS_C);
    __bf16* W2Tp = (__bf16*)((char*)ws + WS_W2T);
    float*  acT  = (float*)((char*)ws + WS_ACT);
    const int e0 = blockIdx.x * 256 + threadIdx.x;

    for (int e = e0; e < H1_ * D_; e += 2048) {
        int h = e >> 6, f = e & 63;
        float wb = W1[(64  + f) * H1_ + h];
        float wc = W1[(128 + f) * H1_ + h];
        float wd = W1[(192 + f) * H1_ + h];
        float wa = W1[f * H1_ + h];
        A[e]   = (__bf16)(wb - wc);
        C[e]   = (__bf16)wd;
        acT[e] = wa + wc;
    }
    for (int e = e0; e < 48 * WSTR; e += 2048) {
        int g = e / WSTR, h = e - g * WSTR;
        W2Tp[e] = (g < H2_ && h < H1_) ? (__bf16)W2[h * H2_ + g] : (__bf16)0.0f;
    }
}

// ---------- main: one batch per 2-wave block, per-wave flash, 3 barriers ----------
__global__ __launch_bounds__(128, 3)
void attn_din13(const float* __restrict__ query,
                const float* __restrict__ key,
                const int*   __restrict__ mask,
                const float* __restrict__ b1,
                const float* __restrict__ b2,
                const float* __restrict__ W3,
                const float* __restrict__ b3,
                const void*  __restrict__ ws,
                float* __restrict__ out)
{
    __shared__ __align__(16) __bf16 s_V[H1_ * VSTR];     // 11520 B (block-shared)
    __shared__ __align__(16) __bf16 s_h1[2][16 * HSTR];  //  6656 B (per-wave)
    __shared__ __align__(16) float  s_q[D_];             //   256 B
    __shared__ float s_base[H1_];                         //   320 B
    __shared__ float s_sc16[2][16];                       //   128 B
    __shared__ float s_part[2][D_];                       //   512 B
    __shared__ float s_ml[2][2];
    // ~19.4 KB -> 6 blocks/CU (wave-limited at 3/SIMD)

    const int tid  = threadIdx.x;          // 0..127
    const int lane = tid & 63;
    const int w    = tid >> 6;             // wave 0/1
    const int c16  = lane & 15;
    const int g16  = lane >> 4;
    const int b    = blockIdx.x;

    const int   mv     = mask[b];
    const int   ntiles = (mv + 15) >> 4;
    const float b3v    = b3[0];
    const float* kb = key + (size_t)b * T_ * D_;

    const __bf16* wsA   = (const __bf16*)((const char*)ws + WS_A);
    const __bf16* wsC   = (const __bf16*)((const char*)ws + WS_C);
    const __bf16* wsW2T = (const __bf16*)((const char*)ws + WS_W2T);
    const float*  wsacT = (const float*) ((const char*)ws + WS_ACT);

    // ---- stage q; W2T fragments into registers (both waves) ----
    if (tid < D_) s_q[tid] = query[b * D_ + tid];

    bf16x8 bw[3][3];
    #pragma unroll
    for (int nt = 0; nt < 3; ++nt)
        #pragma unroll
        for (int ks = 0; ks < 3; ++ks)
            bw[nt][ks] = *(const bf16x8*)&wsW2T[(nt * 16 + c16) * WSTR + ks * 32 + g16 * 8];

    float b2c[3], w3c[3];
    #pragma unroll
    for (int nt = 0; nt < 3; ++nt) {
        int g = nt * 16 + c16;
        b2c[nt] = (g < H2_) ? b2[g] : 0.0f;
        w3c[nt] = (g < H2_) ? W3[g] : 0.0f;
    }
    __syncthreads();   // q visible

    // ---- joint V = A + q*C (640 chunks over 128 threads) ----
    #pragma unroll
    for (int i = 0; i < 5; ++i) {
        int e = tid + 128 * i;
        int h = e >> 3, f8 = e & 7;
        bf16x8 a8 = *(const bf16x8*)&wsA[e * 8];
        bf16x8 c8 = *(const bf16x8*)&wsC[e * 8];
        f32x4 q0 = *(const f32x4*)&s_q[f8 * 8];
        f32x4 q1 = *(const f32x4*)&s_q[f8 * 8 + 4];
        bf16x8 v8;
        v8[0] = (__bf16)((float)a8[0] + q0[0] * (float)c8[0]);
        v8[1] = (__bf16)((float)a8[1] + q0[1] * (float)c8[1]);
        v8[2] = (__bf16)((float)a8[2] + q0[2] * (float)c8[2]);
        v8[3] = (__bf16)((float)a8[3] + q0[3] * (float)c8[3]);
        v8[4] = (__bf16)((float)a8[4] + q1[0] * (float)c8[4]);
        v8[5] = (__bf16)((float)a8[5] + q1[1] * (float)c8[5]);
        v8[6] = (__bf16)((float)a8[6] + q1[2] * (float)c8[6]);
        v8[7] = (__bf16)((float)a8[7] + q1[3] * (float)c8[7]);
        *(bf16x8*)&s_V[h * VSTR + f8 * 8] = v8;
    }

    // ---- base[h] (threads 0..79) ----
    if (tid < H1_) {
        float a0 = b1[tid], a1 = 0.0f, a2 = 0.0f, a3 = 0.0f;
        const f32x4* row = (const f32x4*)&wsacT[tid * D_];
        #pragma unroll
        for (int f4 = 0; f4 < 16; ++f4) {
            f32x4 v  = row[f4];
            f32x4 q4 = *(const f32x4*)&s_q[f4 * 4];
            a0 = fmaf(q4[0], v[0], a0);
            a1 = fmaf(q4[1], v[1], a1);
            a2 = fmaf(q4[2], v[2], a2);
            a3 = fmaf(q4[3], v[3], a3);
        }
        s_base[tid] = (a0 + a1) + (a2 + a3);
    }

    // ---- zero h1 pad cols 80..95 (own wave region) ----
    {
        int row = lane & 15, c0 = 80 + (lane >> 4) * 4;
        *(uint2*)&s_h1[w][row * HSTR + c0] = make_uint2(0u, 0u);
    }
    __syncthreads();   // V, base visible

    float base_c[5];
    #pragma unroll
    for (int nt = 0; nt < 5; ++nt) base_c[nt] = s_base[nt * 16 + c16];
    __bf16* myh = &s_h1[w][0];

    // ---- prologue key load for first own-parity tile (clamped rows) ----
    float4 u0, u1, u2, u3;
    {
        int tr = w * 16 + c16;
        const float* kr = kb + (size_t)((tr < T_) ? tr : (T_ - 1)) * D_ + g16 * 8;
        u0 = *(const float4*)(kr);
        u1 = *(const float4*)(kr + 4);
        u2 = *(const float4*)(kr + 32);
        u3 = *(const float4*)(kr + 36);
    }

    // ---- per-wave flash state ----
    float o00,o01,o02,o03,o04,o05,o06,o07,o08,o09,o10,o11,o12,o13,o14,o15;
    o00=o01=o02=o03=o04=o05=o06=o07=o08=o09=o10=o11=o12=o13=o14=o15=0.0f;
    float m_run = -1e30f, l_run = 0.0f;

    // ---------------- main loop: own-parity tiles, no barriers ----------------
    for (int tt = w; tt < ntiles; tt += 2) {
        // convert to bf16 frags, freeing u for prefetch overwrite
        bf16x8 af0, af1;
        af0[0] = (__bf16)u0.x; af0[1] = (__bf16)u0.y; af0[2] = (__bf16)u0.z; af0[3] = (__bf16)u0.w;
        af0[4] = (__bf16)u1.x; af0[5] = (__bf16)u1.y; af0[6] = (__bf16)u1.z; af0[7] = (__bf16)u1.w;
        af1[0] = (__bf16)u2.x; af1[1] = (__bf16)u2.y; af1[2] = (__bf16)u2.z; af1[3] = (__bf16)u2.w;
        af1[4] = (__bf16)u3.x; af1[5] = (__bf16)u3.y; af1[6] = (__bf16)u3.z; af1[7] = (__bf16)u3.w;

        // T14 prefetch next own-parity tile
        if (tt + 2 < ntiles) {
            int tr = (tt + 2) * 16 + c16;
            const float* kr = kb + (size_t)((tr < T_) ? tr : (T_ - 1)) * D_ + g16 * 8;
            u0 = *(const float4*)(kr);
            u1 = *(const float4*)(kr + 4);
            u2 = *(const float4*)(kr + 32);
            u3 = *(const float4*)(kr + 36);
        }

        // layer 1 -> sigmoid -> h1 (own-wave region; B from shared s_V)
        #pragma unroll
        for (int nt = 0; nt < 5; ++nt) {
            float bb = base_c[nt];
            f32x4 c = { bb, bb, bb, bb };
            bf16x8 bv0 = *(const bf16x8*)&s_V[(nt * 16 + c16) * VSTR + g16 * 8];
            bf16x8 bv1 = *(const bf16x8*)&s_V[(nt * 16 + c16) * VSTR + 32 + g16 * 8];
            c = __builtin_amdgcn_mfma_f32_16x16x32_bf16(af0, bv0, c, 0, 0, 0);
            c = __builtin_amdgcn_mfma_f32_16x16x32_bf16(af1, bv1, c, 0, 0, 0);
            #pragma unroll
            for (int r = 0; r < 4; ++r)
                myh[(g16 * 4 + r) * HSTR + nt * 16 + c16] = (__bf16)sigmoidf_(c[r]);
        }

        // layer 2 (k=0..95 incl. zero pad), B from registers
        bf16x8 a2_0 = *(const bf16x8*)&myh[c16 * HSTR + g16 * 8];
        bf16x8 a2_1 = *(const bf16x8*)&myh[c16 * HSTR + 32 + g16 * 8];
        bf16x8 a2_2 = *(const bf16x8*)&myh[c16 * HSTR + 64 + g16 * 8];
        f32x4 acc2[3];
        #pragma unroll
        for (int nt = 0; nt < 3; ++nt) {
            float bb = b2c[nt];
            f32x4 c = { bb, bb, bb, bb };
            c = __builtin_amdgcn_mfma_f32_16x16x32_bf16(a2_0, bw[nt][0], c, 0, 0, 0);
            c = __builtin_amdgcn_mfma_f32_16x16x32_bf16(a2_1, bw[nt][1], c, 0, 0, 0);
            c = __builtin_amdgcn_mfma_f32_16x16x32_bf16(a2_2, bw[nt][2], c, 0, 0, 0);
            acc2[nt] = c;
        }

        // layer 3 + masked score -> s_sc16 (own wave)
        const int tb = tt * 16;
        #pragma unroll
        for (int r = 0; r < 4; ++r) {
            float partial = sigmoidf_(acc2[0][r]) * w3c[0]
                          + sigmoidf_(acc2[1][r]) * w3c[1]
                          + sigmoidf_(acc2[2][r]) * w3c[2];
            partial += __shfl_xor(partial, 1);
            partial += __shfl_xor(partial, 2);
            partial += __shfl_xor(partial, 4);
            partial += __shfl_xor(partial, 8);
            if (c16 == 0) {
                int t = tb + g16 * 4 + r;
                s_sc16[w][g16 * 4 + r] = (t < mv) ? (partial + b3v) * 0.125f : -1e30f;
            }
        }

        // online softmax update (lane's row t = tb + c16; key values from af)
        float s = s_sc16[w][c16];
        float tm = s;
        tm = fmaxf(tm, __shfl_xor(tm, 1));
        tm = fmaxf(tm, __shfl_xor(tm, 2));
        tm = fmaxf(tm, __shfl_xor(tm, 4));
        tm = fmaxf(tm, __shfl_xor(tm, 8));
        float m_new = fmaxf(m_run, tm);
        float alpha = __expf(m_run - m_new);
        float p = __expf(s - m_new);
        float psum = p;
        psum += __shfl_xor(psum, 1);
        psum += __shfl_xor(psum, 2);
        psum += __shfl_xor(psum, 4);
        psum += __shfl_xor(psum, 8);
        l_run = l_run * alpha + psum;
        o00 = fmaf(p, (float)af0[0], o00 * alpha);  o01 = fmaf(p, (float)af0[1], o01 * alpha);
        o02 = fmaf(p, (float)af0[2], o02 * alpha);  o03 = fmaf(p, (float)af0[3], o03 * alpha);
        o04 = fmaf(p, (float)af0[4], o04 * alpha);  o05 = fmaf(p, (float)af0[5], o05 * alpha);
        o06 = fmaf(p, (float)af0[6], o06 * alpha);  o07 = fmaf(p, (float)af0[7], o07 * alpha);
        o08 = fmaf(p, (float)af1[0], o08 * alpha);  o09 = fmaf(p, (float)af1[1], o09 * alpha);
        o10 = fmaf(p, (float)af1[2], o10 * alpha);  o11 = fmaf(p, (float)af1[3], o11 * alpha);
        o12 = fmaf(p, (float)af1[4], o12 * alpha);  o13 = fmaf(p, (float)af1[5], o13 * alpha);
        o14 = fmaf(p, (float)af1[6], o14 * alpha);  o15 = fmaf(p, (float)af1[7], o15 * alpha);
        m_run = m_new;
    }

    // ---------------- per-wave finalize: reduce o over c16 lanes ----------------
    #define ORED(X) X += __shfl_xor(X,1); X += __shfl_xor(X,2); X += __shfl_xor(X,4); X += __shfl_xor(X,8);
    ORED(o00) ORED(o01) ORED(o02) ORED(o03) ORED(o04) ORED(o05) ORED(o06) ORED(o07)
    ORED(o08) ORED(o09) ORED(o10) ORED(o11) ORED(o12) ORED(o13) ORED(o14) ORED(o15)
    #undef ORED
    if (c16 == 0) {
        float* sp = &s_part[w][0];
        sp[g16 * 8 + 0] = o00;  sp[g16 * 8 + 1] = o01;
        sp[g16 * 8 + 2] = o02;  sp[g16 * 8 + 3] = o03;
        sp[g16 * 8 + 4] = o04;  sp[g16 * 8 + 5] = o05;
        sp[g16 * 8 + 6] = o06;  sp[g16 * 8 + 7] = o07;
        sp[32 + g16 * 8 + 0] = o08;  sp[32 + g16 * 8 + 1] = o09;
        sp[32 + g16 * 8 + 2] = o10;  sp[32 + g16 * 8 + 3] = o11;
        sp[32 + g16 * 8 + 4] = o12;  sp[32 + g16 * 8 + 5] = o13;
        sp[32 + g16 * 8 + 6] = o14;  sp[32 + g16 * 8 + 7] = o15;
    }
    if (lane == 0) { s_ml[w][0] = m_run; s_ml[w][1] = l_run; }
    __syncthreads();

    // ---------------- cross-wave flash merge (threads 0..63) ----------------
    if (tid < D_) {
        float m0 = s_ml[0][0], l0 = s_ml[0][1];
        float m1 = s_ml[1][0], l1 = s_ml[1][1];
        float mm = fmaxf(m0, m1);
        float f0 = __expf(m0 - mm);
        float f1 = __expf(m1 - mm);
        float tot = l0 * f0 + l1 * f1;
        out[b * D_ + tid] = (s_part[0][tid] * f0 + s_part[1][tid] * f1)
                          * __builtin_amdgcn_rcpf(tot);
    }
}

extern "C" void kernel_launch(void* const* d_in, const int* in_sizes, int n_in,
                              void* d_out, int out_size, void* d_ws, size_t ws_size,
                              hipStream_t stream)
{
    const float* query = (const float*)d_in[0];
    const float* key   = (const float*)d_in[1];
    const int*   mask  = (const int*)  d_in[2];
    const float* W1    = (const float*)d_in[3];
    const float* b1    = (const float*)d_in[4];
    const float* W2    = (const float*)d_in[5];
    const float* b2    = (const float*)d_in[6];
    const float* W3    = (const float*)d_in[7];
    const float* b3    = (const float*)d_in[8];
    float* out = (float*)d_out;

    prep_kernel<<<8, 256, 0, stream>>>(W1, W2, d_ws);
    attn_din13<<<B_, 128, 0, stream>>>(query, key, mask, b1, b2, W3, b3, d_ws, out);
}